// Round 5
// baseline (153.734 us; speedup 1.0000x reference)
//
#include <hip/hip_runtime.h>
#include <math.h>

#define IN_DIM 64
#define HH 4
#define CC 128   /* HH*DD */
#define NEG_SLOPE 0.1f

typedef __attribute__((ext_vector_type(8))) short short8;
typedef __attribute__((ext_vector_type(4))) float f32x4;

__device__ __forceinline__ float leaky(float v) { return v >= 0.f ? v : NEG_SLOPE * v; }

// bf16 helpers (round-to-nearest-even)
__device__ __forceinline__ unsigned f2bf(float f) {
  unsigned u = __float_as_uint(f);
  unsigned r = u + 0x7FFFu + ((u >> 16) & 1u);
  return r >> 16;
}
__device__ __forceinline__ float bflo(unsigned v) { return __uint_as_float(v << 16); }
__device__ __forceinline__ float bfhi(unsigned v) { return __uint_as_float(v & 0xFFFF0000u); }

// ---------------- Kernel 0: build swizzled bf16 W^T image (128 rows x 32 u32) ------
__global__ void k_prepw(const float* __restrict__ W, unsigned* __restrict__ wt) {
  int tid = blockIdx.x * 256 + threadIdx.x;
  if (tid >= 128 * 32) return;
  int n = tid >> 5;
  int r = tid & 31;
  int b = r >> 2, h = r & 3;
  int k = b * 8 + h * 2;
  unsigned lo = f2bf(W[k * CC + n]);
  unsigned hi = f2bf(W[(k + 1) * CC + n]);
  wt[n * 32 + (b ^ (n & 7)) * 4 + h] = lo | (hi << 16);
}

// ---------------- Kernel 1: MFMA projection: feat(bf16), el/er (fp32) ----------------
__global__ __launch_bounds__(256) void k_project(
    const float* __restrict__ x, const unsigned* __restrict__ wt,
    const float* __restrict__ attn_l, const float* __restrict__ attn_r,
    unsigned* __restrict__ featbf, float* __restrict__ el, float* __restrict__ er,
    int N)
{
  __shared__ unsigned Wlds[4096];   // 16 KB swizzled Wt bf16
  __shared__ float Al[CC], Ar[CC];
  int t = threadIdx.x;
  {
    const uint4* s = (const uint4*)wt;
    uint4* d = (uint4*)Wlds;
#pragma unroll
    for (int i = 0; i < 4; ++i) d[t + 256 * i] = s[t + 256 * i];
  }
  if (t < CC) { Al[t] = attn_l[t]; Ar[t] = attn_r[t]; }
  __syncthreads();

  int lane = t & 63;
  int l4 = lane >> 4, l16 = lane & 15;
  int node = blockIdx.x * 64 + (t >> 6) * 16 + l16;
  bool valid = node < N;
  int nrow = valid ? node : 0;

  short8 bfr[2];
#pragma unroll
  for (int s = 0; s < 2; ++s) {
    const float4* xp = (const float4*)&x[(size_t)nrow * 64 + s * 32 + l4 * 8];
    float4 xa = xp[0], xb = xp[1];
    union { short8 v; unsigned u[4]; } pk;
    pk.u[0] = f2bf(xa.x) | (f2bf(xa.y) << 16);
    pk.u[1] = f2bf(xa.z) | (f2bf(xa.w) << 16);
    pk.u[2] = f2bf(xb.x) | (f2bf(xb.y) << 16);
    pk.u[3] = f2bf(xb.z) | (f2bf(xb.w) << 16);
    bfr[s] = pk.v;
  }

  f32x4 acc[8];
#pragma unroll
  for (int c = 0; c < 8; ++c) acc[c] = (f32x4){0.f, 0.f, 0.f, 0.f};

#pragma unroll
  for (int c = 0; c < 8; ++c) {
    int n0 = c * 16 + l16;
    int sw = n0 & 7;
#pragma unroll
    for (int s = 0; s < 2; ++s) {
      int b = s * 4 + l4;
      union { short8 v; uint4 q; } af;
      af.q = *(const uint4*)&Wlds[n0 * 32 + (b ^ sw) * 4];
      acc[c] = __builtin_amdgcn_mfma_f32_16x16x32_bf16(af.v, bfr[s], acc[c], 0, 0, 0);
    }
  }

  if (valid) {
#pragma unroll
    for (int c = 0; c < 8; ++c) {
      unsigned u0 = f2bf(acc[c][0]) | (f2bf(acc[c][1]) << 16);
      unsigned u1 = f2bf(acc[c][2]) | (f2bf(acc[c][3]) << 16);
      *(uint2*)&featbf[(size_t)node * 64 + c * 8 + l4 * 2] = make_uint2(u0, u1);
    }
  }

  float pl[4], pr[4];
#pragma unroll
  for (int h = 0; h < 4; ++h) {
    float sl = 0.f, sr = 0.f;
#pragma unroll
    for (int ct = 0; ct < 2; ++ct) {
      int c = 2 * h + ct;
      int cb = c * 16 + l4 * 4;
#pragma unroll
      for (int r = 0; r < 4; ++r) {
        sl = fmaf(acc[c][r], Al[cb + r], sl);
        sr = fmaf(acc[c][r], Ar[cb + r], sr);
      }
    }
    sl += __shfl_xor(sl, 16, 64); sl += __shfl_xor(sl, 32, 64);
    sr += __shfl_xor(sr, 16, 64); sr += __shfl_xor(sr, 32, 64);
    pl[h] = sl; pr[h] = sr;
  }
  if (l4 == 0 && valid) {
    *(float4*)&el[(size_t)node * 4] = make_float4(pl[0], pl[1], pl[2], pl[3]);
    *(float4*)&er[(size_t)node * 4] = make_float4(pr[0], pr[1], pr[2], pr[3]);
  }
}

// ---------------- counting-sort CSR build (bucket = dst >> 8) ----------------
__global__ __launch_bounds__(256) void k_bhist(const int* __restrict__ dst,
                                               int* __restrict__ bcnt, int E, int NB) {
  __shared__ int lh[512];
  for (int i = threadIdx.x; i < NB; i += 256) lh[i] = 0;
  __syncthreads();
  int stride = gridDim.x * 256;
  for (int i = blockIdx.x * 256 + threadIdx.x; i < E; i += stride)
    atomicAdd(&lh[dst[i] >> 8], 1);
  __syncthreads();
  for (int i = threadIdx.x; i < NB; i += 256) {
    int c = lh[i];
    if (c) atomicAdd(&bcnt[i], c);
  }
}

__global__ __launch_bounds__(512) void k_bscan(const int* __restrict__ bcnt,
                                               int* __restrict__ gbase,
                                               int* __restrict__ gcursor, int NB) {
  __shared__ int sh[512];
  int t = threadIdx.x;
  int v = (t < NB) ? bcnt[t] : 0;
  sh[t] = v;
  __syncthreads();
  for (int off = 1; off < 512; off <<= 1) {
    int a = (t >= off) ? sh[t - off] : 0;
    __syncthreads();
    sh[t] += a;
    __syncthreads();
  }
  if (t < NB) {
    int e = sh[t] - v;
    gbase[t] = e;
    gcursor[t] = e;
  }
}

// bin 8192 edges/block into buckets; payload = (src | dst_local<<20, w)
__global__ __launch_bounds__(512) void k_binA(const int* __restrict__ src,
                                              const int* __restrict__ dst,
                                              const float* __restrict__ w,
                                              int* __restrict__ gcursor,
                                              uint2* __restrict__ bkt, int E, int NB) {
  __shared__ int lh[512];
  __shared__ int lbase[512];
  int t = threadIdx.x;
  for (int i = t; i < NB; i += 512) lh[i] = 0;
  __syncthreads();
  long eb = (long)blockIdx.x * 8192;
  int b[16]; int r[16]; unsigned px[16]; unsigned pw[16];
#pragma unroll
  for (int i = 0; i < 16; ++i) {
    long e = eb + t + i * 512;
    bool v = e < E;
    int d = v ? dst[e] : 0;
    b[i] = d >> 8;
    px[i] = v ? ((unsigned)src[e] | ((unsigned)(d & 255) << 20)) : 0u;
    pw[i] = v ? ((const unsigned*)w)[e] : 0u;
    r[i] = v ? atomicAdd(&lh[b[i]], 1) : -1;
  }
  __syncthreads();
  for (int i = t; i < NB; i += 512) {
    int c = lh[i];
    lbase[i] = c ? atomicAdd(&gcursor[i], c) : 0;
  }
  __syncthreads();
#pragma unroll
  for (int i = 0; i < 16; ++i)
    if (r[i] >= 0) bkt[lbase[b[i]] + r[i]] = make_uint2(px[i], pw[i]);
}

// per-bucket fine scatter: LDS node-hist -> scan -> offs + sp
__global__ __launch_bounds__(256) void k_binB(const uint2* __restrict__ bkt,
                                              const int* __restrict__ bcnt,
                                              const int* __restrict__ gbase,
                                              int* __restrict__ offs,
                                              int2* __restrict__ sp,
                                              int N, int E, int NB) {
  __shared__ int lh[256], sc[256], lcur[256];
  int b = blockIdx.x;
  int t = threadIdx.x;
  int base_b = gbase[b];
  int cnt_b = bcnt[b];
  lh[t] = 0;
  __syncthreads();
  for (int e = t; e < cnt_b; e += 256) {
    uint2 p = bkt[base_b + e];
    atomicAdd(&lh[(p.x >> 20) & 255], 1);
  }
  __syncthreads();
  int v = lh[t];
  sc[t] = v;
  __syncthreads();
  for (int off = 1; off < 256; off <<= 1) {
    int a = (t >= off) ? sc[t - off] : 0;
    __syncthreads();
    sc[t] += a;
    __syncthreads();
  }
  int excl = sc[t] - v;
  lcur[t] = excl;
  int n0 = b << 8;
  if (n0 + t < N) offs[n0 + t] = base_b + excl;
  if (b == NB - 1 && t == 0) offs[N] = E;
  __syncthreads();
  for (int e = t; e < cnt_b; e += 256) {
    uint2 p = bkt[base_b + e];
    int d = (p.x >> 20) & 255;
    int pos = atomicAdd(&lcur[d], 1);
    sp[base_b + pos] = make_int2((int)(p.x & 0xFFFFFu), (int)p.y);
  }
}

// ---------------- Kernel 3: per-node softmax + weighted gather-sum ----------------
// wave per node. FMA loop: 4 edges/iter, 16 lanes/edge, uint4 (8 bf16 cols)/lane.
__global__ __launch_bounds__(256) void k_aggregate(
    const int* __restrict__ offs, const int2* __restrict__ sp,
    const float* __restrict__ el, const float* __restrict__ er,
    const char* __restrict__ featbf, float* __restrict__ out, int N)
{
  __shared__ int    s_lds[4][64];   // src byte offsets (src<<8)
  __shared__ float4 a_lds[4][64];   // per-edge alphas (4 heads)

  int t = threadIdx.x;
  int lane = t & 63, wv = t >> 6;
  int n = blockIdx.x * 4 + wv;
  if (n >= N) return;

  int off0 = offs[n], off1 = offs[n + 1];
  int deg = off1 - off0;
  int q = lane >> 4;             // quarter 0..3 (edge slot within iter)
  int l16 = lane & 15;
  int h4 = l16 >> 2;             // head owning this lane's 8 cols
  const char* featl = featbf + l16 * 16;
  float acc[8] = {0.f, 0.f, 0.f, 0.f, 0.f, 0.f, 0.f, 0.f};

  if (deg > 0) {
    float4 erv = *reinterpret_cast<const float4*>(&er[n * HH]);
    if (deg <= 64) {
      bool act = lane < deg;
      int2 p = sp[off0 + (act ? lane : 0)];
      int s = p.x;
      float wgt = __int_as_float(p.y);
      float4 elv = *reinterpret_cast<const float4*>(&el[s * HH]);
      float e0 = act ? leaky(elv.x + erv.x) * wgt : -INFINITY;
      float e1 = act ? leaky(elv.y + erv.y) * wgt : -INFINITY;
      float e2 = act ? leaky(elv.z + erv.z) * wgt : -INFINITY;
      float e3 = act ? leaky(elv.w + erv.w) * wgt : -INFINITY;
      float m0 = e0, m1 = e1, m2 = e2, m3 = e3;
#pragma unroll
      for (int d = 32; d >= 1; d >>= 1) {
        m0 = fmaxf(m0, __shfl_xor(m0, d, 64));
        m1 = fmaxf(m1, __shfl_xor(m1, d, 64));
        m2 = fmaxf(m2, __shfl_xor(m2, d, 64));
        m3 = fmaxf(m3, __shfl_xor(m3, d, 64));
      }
      float x0 = act ? __expf(e0 - m0) : 0.f;
      float x1 = act ? __expf(e1 - m1) : 0.f;
      float x2 = act ? __expf(e2 - m2) : 0.f;
      float x3 = act ? __expf(e3 - m3) : 0.f;
      float d0 = x0, d1 = x1, d2 = x2, d3 = x3;
#pragma unroll
      for (int d = 32; d >= 1; d >>= 1) {
        d0 += __shfl_xor(d0, d, 64);
        d1 += __shfl_xor(d1, d, 64);
        d2 += __shfl_xor(d2, d, 64);
        d3 += __shfl_xor(d3, d, 64);
      }
      float a0 = x0 * __builtin_amdgcn_rcpf(d0);
      float a1 = x1 * __builtin_amdgcn_rcpf(d1);
      float a2 = x2 * __builtin_amdgcn_rcpf(d2);
      float a3 = x3 * __builtin_amdgcn_rcpf(d3);
      s_lds[wv][lane] = s << 8;
      a_lds[wv][lane] = make_float4(a0, a1, a2, a3);

      int nq = (deg + 3) >> 2;
#pragma unroll 2
      for (int tt = 0; tt < nq; ++tt) {
        int idx = 4 * tt + q;
        bool vv = idx < deg;
        int ic = vv ? idx : 0;
        float a = vv ? reinterpret_cast<const float*>(&a_lds[wv][ic])[h4] : 0.f;
        int boff = s_lds[wv][ic];
        uint4 f = *reinterpret_cast<const uint4*>(featl + boff);
        acc[0] = fmaf(a, bflo(f.x), acc[0]);
        acc[1] = fmaf(a, bfhi(f.x), acc[1]);
        acc[2] = fmaf(a, bflo(f.y), acc[2]);
        acc[3] = fmaf(a, bfhi(f.y), acc[3]);
        acc[4] = fmaf(a, bflo(f.z), acc[4]);
        acc[5] = fmaf(a, bfhi(f.z), acc[5]);
        acc[6] = fmaf(a, bflo(f.w), acc[6]);
        acc[7] = fmaf(a, bfhi(f.w), acc[7]);
      }
    } else {
      // chunked fallback (deg > 64): 3 passes
      float m0 = -INFINITY, m1 = -INFINITY, m2 = -INFINITY, m3 = -INFINITY;
      for (int base = off0; base < off1; base += 64) {
        int j = base + lane;
        bool act = j < off1;
        int2 p = sp[act ? j : off0];
        float wgt = __int_as_float(p.y);
        float4 elv = *reinterpret_cast<const float4*>(&el[p.x * HH]);
        float e0 = act ? leaky(elv.x + erv.x) * wgt : -INFINITY;
        float e1 = act ? leaky(elv.y + erv.y) * wgt : -INFINITY;
        float e2 = act ? leaky(elv.z + erv.z) * wgt : -INFINITY;
        float e3 = act ? leaky(elv.w + erv.w) * wgt : -INFINITY;
        m0 = fmaxf(m0, e0); m1 = fmaxf(m1, e1);
        m2 = fmaxf(m2, e2); m3 = fmaxf(m3, e3);
      }
#pragma unroll
      for (int d = 32; d >= 1; d >>= 1) {
        m0 = fmaxf(m0, __shfl_xor(m0, d, 64));
        m1 = fmaxf(m1, __shfl_xor(m1, d, 64));
        m2 = fmaxf(m2, __shfl_xor(m2, d, 64));
        m3 = fmaxf(m3, __shfl_xor(m3, d, 64));
      }
      float d0 = 0.f, d1 = 0.f, d2 = 0.f, d3 = 0.f;
      for (int base = off0; base < off1; base += 64) {
        int j = base + lane;
        bool act = j < off1;
        int2 p = sp[act ? j : off0];
        float wgt = __int_as_float(p.y);
        float4 elv = *reinterpret_cast<const float4*>(&el[p.x * HH]);
        float e0 = leaky(elv.x + erv.x) * wgt;
        float e1 = leaky(elv.y + erv.y) * wgt;
        float e2 = leaky(elv.z + erv.z) * wgt;
        float e3 = leaky(elv.w + erv.w) * wgt;
        d0 += act ? __expf(e0 - m0) : 0.f;
        d1 += act ? __expf(e1 - m1) : 0.f;
        d2 += act ? __expf(e2 - m2) : 0.f;
        d3 += act ? __expf(e3 - m3) : 0.f;
      }
#pragma unroll
      for (int d = 32; d >= 1; d >>= 1) {
        d0 += __shfl_xor(d0, d, 64);
        d1 += __shfl_xor(d1, d, 64);
        d2 += __shfl_xor(d2, d, 64);
        d3 += __shfl_xor(d3, d, 64);
      }
      float i0 = __builtin_amdgcn_rcpf(d0), i1 = __builtin_amdgcn_rcpf(d1);
      float i2 = __builtin_amdgcn_rcpf(d2), i3 = __builtin_amdgcn_rcpf(d3);
      for (int base = off0; base < off1; base += 64) {
        int j = base + lane;
        bool act = j < off1;
        int2 p = sp[act ? j : off0];
        float wgt = __int_as_float(p.y);
        float4 elv = *reinterpret_cast<const float4*>(&el[p.x * HH]);
        float e0 = leaky(elv.x + erv.x) * wgt;
        float e1 = leaky(elv.y + erv.y) * wgt;
        float e2 = leaky(elv.z + erv.z) * wgt;
        float e3 = leaky(elv.w + erv.w) * wgt;
        float a0 = act ? __expf(e0 - m0) * i0 : 0.f;
        float a1 = act ? __expf(e1 - m1) * i1 : 0.f;
        float a2 = act ? __expf(e2 - m2) * i2 : 0.f;
        float a3 = act ? __expf(e3 - m3) * i3 : 0.f;
        s_lds[wv][lane] = p.x << 8;
        a_lds[wv][lane] = make_float4(a0, a1, a2, a3);
        int cnt = off1 - base; if (cnt > 64) cnt = 64;
        int nq = (cnt + 3) >> 2;
#pragma unroll 2
        for (int tt = 0; tt < nq; ++tt) {
          int idx = 4 * tt + q;
          bool vv = idx < cnt;
          int ic = vv ? idx : 0;
          float a = vv ? reinterpret_cast<const float*>(&a_lds[wv][ic])[h4] : 0.f;
          int boff = s_lds[wv][ic];
          uint4 f = *reinterpret_cast<const uint4*>(featl + boff);
          acc[0] = fmaf(a, bflo(f.x), acc[0]);
          acc[1] = fmaf(a, bfhi(f.x), acc[1]);
          acc[2] = fmaf(a, bflo(f.y), acc[2]);
          acc[3] = fmaf(a, bfhi(f.y), acc[3]);
          acc[4] = fmaf(a, bflo(f.z), acc[4]);
          acc[5] = fmaf(a, bfhi(f.z), acc[5]);
          acc[6] = fmaf(a, bflo(f.w), acc[6]);
          acc[7] = fmaf(a, bfhi(f.w), acc[7]);
        }
      }
    }
  }
  // combine the 4 quarter-wave accumulators (same cols in lanes l16, l16+16, +32, +48)
#pragma unroll
  for (int i = 0; i < 8; ++i) {
    acc[i] += __shfl_xor(acc[i], 16, 64);
    acc[i] += __shfl_xor(acc[i], 32, 64);
  }
  if (q == 0) {
    float* orow = &out[(size_t)n * CC + l16 * 8];
    *reinterpret_cast<float4*>(orow)     = make_float4(acc[0], acc[1], acc[2], acc[3]);
    *reinterpret_cast<float4*>(orow + 4) = make_float4(acc[4], acc[5], acc[6], acc[7]);
  }
}

// ---------------- launch ----------------
extern "C" void kernel_launch(void* const* d_in, const int* in_sizes, int n_in,
                              void* d_out, int out_size, void* d_ws, size_t ws_size,
                              hipStream_t stream)
{
  const float* x      = (const float*)d_in[1];
  const int*   src    = (const int*)d_in[2];
  const int*   dst    = (const int*)d_in[3];
  const float* w      = (const float*)d_in[4];
  const float* W_fc   = (const float*)d_in[5];
  const float* attn_l = (const float*)d_in[6];
  const float* attn_r = (const float*)d_in[7];
  float* out = (float*)d_out;

  int N = in_sizes[1] / IN_DIM;
  int E = in_sizes[2];
  int NB = (N + 255) / 256;   // nodes/bucket = 256; NB must be <= 512

  char* p = (char*)d_ws;
  auto alloc = [&](size_t bytes) {
    char* r = p;
    p += (bytes + 255) & ~size_t(255);
    return r;
  };
  unsigned* featbf = (unsigned*)alloc((size_t)N * 64 * 4);   // bf16 x2 packed
  float* el    = (float*)alloc((size_t)N * HH * 4);
  float* er    = (float*)alloc((size_t)N * HH * 4);
  int*   offs  = (int*)alloc((size_t)(N + 1) * 4);
  int*   bcnt  = (int*)alloc(512 * 4);
  int*   gbase = (int*)alloc(512 * 4);
  int*   gcur  = (int*)alloc(512 * 4);
  unsigned* wtswz = (unsigned*)alloc(4096 * 4);
  uint2* bkt   = (uint2*)alloc((size_t)E * 8);
  int2*  sp    = (int2*)alloc((size_t)E * 8);

  hipMemsetAsync(bcnt, 0, 512 * 4, stream);

  k_prepw<<<16, 256, 0, stream>>>(W_fc, wtswz);
  k_project<<<(N + 63) / 64, 256, 0, stream>>>(x, wtswz, attn_l, attn_r, featbf, el, er, N);
  k_bhist<<<256, 256, 0, stream>>>(dst, bcnt, E, NB);
  k_bscan<<<1, 512, 0, stream>>>(bcnt, gbase, gcur, NB);
  k_binA<<<(E + 8191) / 8192, 512, 0, stream>>>(src, dst, w, gcur, bkt, E, NB);
  k_binB<<<NB, 256, 0, stream>>>(bkt, bcnt, gbase, offs, sp, N, E, NB);
  k_aggregate<<<(N + 3) / 4, 256, 0, stream>>>(offs, sp, el, er, (const char*)featbf, out, N);
}